// Round 9
// baseline (116.158 us; speedup 1.0000x reference)
//
#include <hip/hip_runtime.h>

// MyConvT: masked ConvTranspose2d, B=8, Cin=192, Cout=128, 64x64 -> 128x128,
// K=5, S=2, P=2, OP=1.  out = pooled_mask ? (convT(x,w) + bias) : 0
// Round 7/8: block = (b, oy-pair) computes ALL 4 parity classes (identical
// work per block, grid 256 = 1/CU). 8 waves = 4 classes x 2 oy rows; wave =
// 128co x 64owp (mi8 x ti4, 375 B/MFMA), 2 waves/SIMD, SIMD pairs
// {00,11},{01,10} => 13/12/12/13 tap-steps per SIMD. No per-tap barriers;
// 3 ci64 rounds with one barrier each. x: 4-plane 36KB LDS double buffer
// (XOR-swizzled, r5-verified pattern); w: L2->VGPR af stream, half-tap-ahead
// double buffer (prefetch window 1242 cy >> L2 latency). Both pw parities
// store from the same block => stride-2 stores merge in XCD L2.

#define NB   8
#define CIN  192
#define COUT 128
#define HH   64
#define WW   64
#define OHH  128
#define OWW  128
#define MH   132
#define MW   132

#define X4_IYH_S 13824               // shorts per (b,iyH): 3 c3 * 72 rows * 64 ci
#define X4_IYH_B 27648
#define PLANE_LB 9216                // 72 rows * 128 B
#define RBUF_B   36864               // 4 planes per round buffer
#define LDS_B    73728               // 2 round buffers

typedef short bf16x8 __attribute__((ext_vector_type(8)));
typedef float f32x4  __attribute__((ext_vector_type(4)));

struct IC0 { static constexpr int value = 0; };
struct IC1 { static constexpr int value = 1; };

static __device__ __forceinline__ unsigned short f2bf(float f) {
  union { float f; unsigned int u; } a; a.f = f;
  return (unsigned short)((a.u + 0x7fffu + ((a.u >> 16) & 1u)) >> 16);   // RNE
}

#define GLOAD_LDS16(gp, lp) __builtin_amdgcn_global_load_lds(                      \
    (const __attribute__((address_space(1))) void*)(gp),                           \
    (__attribute__((address_space(3))) void*)(lp), 16, 0, 0)

// ---------------- mask 5x5 any-pool -> byte map [B][OH][OW] ----------------
__global__ __launch_bounds__(256) void pool_mask_k(const int* __restrict__ mask,
                                                   unsigned char* __restrict__ many) {
  int idx = blockIdx.x * 256 + threadIdx.x;
  if (idx >= NB * OHH * OWW) return;
  int ow = idx & (OWW - 1);
  int oh = (idx >> 7) & (OHH - 1);
  int b  = idx >> 14;
  const int* mp = mask + (b * MH + oh) * MW + ow;
  int any = 0;
  #pragma unroll
  for (int i = 0; i < 5; ++i)
    #pragma unroll
    for (int j = 0; j < 5; ++j)
      any |= mp[i * MW + j];
  many[idx] = (any != 0) ? 1 : 0;
}

// x transpose: [b][ci][iy][ix] f32 -> x4[b][iyH 66][c3 3][row 72][ci64] bf16
// iyH = iy+1 (0,65 zero halo planes); row = ixm = ix+1 (rows 0,65 zero halo;
// rows 66..71 pad, staged but never read).
__global__ __launch_bounds__(256) void xpose_k(const float* __restrict__ x,
                                               unsigned short* __restrict__ x4) {
  const int b = blockIdx.x / 66, iyH = blockIdx.x % 66;
  const int lane = threadIdx.x & 63, wv = threadIdx.x >> 6;
  unsigned short* pl = x4 + (size_t)(b * 66 + iyH) * X4_IYH_S;

  if (iyH == 0 || iyH == 65) {                       // zero halo plane
    for (int i = threadIdx.x; i < X4_IYH_S / 8; i += 256)
      *(uint4*)(pl + i * 8) = make_uint4(0, 0, 0, 0);
    return;
  }
  const int iy = iyH - 1;
  if (threadIdx.x < 48) {                            // halo rows 0,65 per c3
    int c3 = threadIdx.x >> 4, rr = (threadIdx.x >> 3) & 1, ch = threadIdx.x & 7;
    *(uint4*)(pl + (c3 * 72 + rr * 65) * 64 + ch * 8) = make_uint4(0, 0, 0, 0);
  }
  #pragma unroll
  for (int k = 0; k < 6; ++k) {
    int ci0 = wv * 48 + k * 8;
    int c3 = ci0 >> 6, cr = ci0 & 63;
    unsigned short p[8];
    #pragma unroll
    for (int e = 0; e < 8; ++e)
      p[e] = f2bf(x[(((size_t)b * CIN + ci0 + e) * HH + iy) * WW + lane]);
    uint4 v;
    v.x = (unsigned)p[0] | ((unsigned)p[1] << 16);
    v.y = (unsigned)p[2] | ((unsigned)p[3] << 16);
    v.z = (unsigned)p[4] | ((unsigned)p[5] << 16);
    v.w = (unsigned)p[6] | ((unsigned)p[7] << 16);
    *(uint4*)(pl + ((size_t)c3 * 72 + 1 + lane) * 64 + cr) = v;
  }
}

// w repack: [ci][co][kh][kw] f32 -> w3[tap 25][q 6][co 128][ci32] bf16
__global__ __launch_bounds__(256) void wpack_k(const float* __restrict__ w,
                                               unsigned short* __restrict__ w3) {
  int idx = blockIdx.x * 256 + threadIdx.x;          // 24576 threads
  int c = idx & 31, co = (idx >> 5) & 127, q = idx >> 12;
  int ci = q * 32 + c;
  const float* src = w + (size_t)(ci * COUT + co) * 25;
  #pragma unroll
  for (int tap = 0; tap < 25; ++tap)
    w3[((size_t)(tap * 6 + q) * COUT + co) * 32 + c] = f2bf(src[tap]);
}

// ------------------------------ main kernel --------------------------------
#define MFMA_BF16 __builtin_amdgcn_mfma_f32_16x16x32_bf16

template<int PH, int PW>
__device__ __forceinline__ void round_cls(const char* xsw, const char* wb,
                                          f32x4 (&acc)[8][4],
                                          int l15, int kc, int oys) {
  constexpr int NKW = PW ? 2 : 3;
  constexpr int NKK = PH ? 2 : 3;
  constexpr int T = NKK * NKW;
  bf16x8 af[2][8], bf[2][4];

  auto afL = [&](auto set, int t, auto k2) {
    const int kk = t / NKW, kj = t % NKW;
    const int tap = (PH + 2 * kk) * 5 + PW + 2 * kj;
    const char* ap = wb + (size_t)tap * 49152 + k2.value * 8192;
    #pragma unroll
    for (int mi = 0; mi < 8; ++mi)
      af[set.value][mi] = *(const bf16x8*)(ap + mi * 1024);
  };
  auto bfL = [&](auto set, int t, auto k2) {
    const int kk = t / NKW, kj = t % NKW;
    const int im0 = l15 + 2 - kj;
    const int av = im0 * 128 + (((kc + 4 * k2.value) ^ (im0 & 7)) << 4);
    const char* bp = xsw + (oys + 2 - kk) * PLANE_LB + av;
    #pragma unroll
    for (int ti = 0; ti < 4; ++ti)
      bf[set.value][ti] = *(const bf16x8*)(bp + ti * 2048);
  };
  auto MM = [&](auto set) {
    #pragma unroll
    for (int mi = 0; mi < 8; ++mi)
      #pragma unroll
      for (int ti = 0; ti < 4; ++ti)
        acc[mi][ti] = MFMA_BF16(af[set.value][mi], bf[set.value][ti],
                                acc[mi][ti], 0, 0, 0);
  };

  afL(IC0{}, 0, IC0{});
  bfL(IC0{}, 0, IC0{});
  #pragma unroll 1
  for (int t = 0; t < T; ++t) {
    afL(IC1{}, t, IC1{});                // prefetch half k2=1 of tap t
    bfL(IC1{}, t, IC1{});
    MM(IC0{});                           // compute (t, k2=0)
    const int tn = (t + 1 < T) ? t + 1 : t;
    afL(IC0{}, tn, IC0{});               // prefetch half k2=0 of tap t+1
    bfL(IC0{}, tn, IC0{});
    MM(IC1{});                           // compute (t, k2=1)
  }
}

// grid 256 = (b 8) x (oyq 32), XCD-chunked (one XCD per batch image).
// 512 threads = 8 waves: clsid = wv<4 ? wv : 7-wv, oys = wv>>2 =>
// SIMD0..3 host tap-steps {9+4, 6+6, 6+6, 4+9}.
__global__ __launch_bounds__(512, 2) void convt_mfma(
    const unsigned short* __restrict__ x4, const unsigned short* __restrict__ w3,
    const float* __restrict__ bias, const unsigned char* __restrict__ many,
    float* __restrict__ out) {
  __shared__ char lds[LDS_B];

  const int tid = threadIdx.x, lane = tid & 63, wv = tid >> 6;
  const int l15 = lane & 15, kc = lane >> 4;
  const int lo8 = lane >> 3, l7 = lane & 7;
  const int clsid = (wv < 4) ? wv : 7 - wv, oys = wv >> 2;
  const int sw = (blockIdx.x & 7) * 32 + (blockIdx.x >> 3);
  const int b = sw >> 5, oyq = sw & 31;

  const int voff = l15 * 64 + kc * 16;               // af lane offset (bytes)
  const char* wbv = (const char*)w3 + voff;
  const size_t xbase = ((size_t)b * 66 + 2 * oyq) * X4_IYH_B;

  auto stage = [&](int c3, int buf) {
    #pragma unroll
    for (int i = 0; i < 5; ++i) {
      int idx = wv + 8 * i;                          // 36 chunks of 1KB
      if (idx < 36) {
        int p = idx / 9, ch = idx % 9;
        const char* src = (const char*)x4 + xbase + (size_t)p * X4_IYH_B
                          + c3 * PLANE_LB + ch * 1024 + lo8 * 128 + ((l7 ^ lo8) << 4);
        GLOAD_LDS16(src, lds + buf * RBUF_B + p * PLANE_LB + ch * 1024 + lane * 16);
      }
    }
  };

  f32x4 acc[8][4];
  #pragma unroll
  for (int i = 0; i < 8; ++i)
    #pragma unroll
    for (int j = 0; j < 4; ++j)
      acc[i][j] = (f32x4){0.f, 0.f, 0.f, 0.f};

  stage(0, 0);
  __syncthreads();

  #pragma unroll 1
  for (int c3 = 0; c3 < 3; ++c3) {
    if (c3 < 2) stage(c3 + 1, (c3 + 1) & 1);
    const char* xsw = lds + (c3 & 1) * RBUF_B;
    const char* wb  = wbv + c3 * 16384;
    if      (clsid == 0) round_cls<0, 0>(xsw, wb, acc, l15, kc, oys);
    else if (clsid == 1) round_cls<0, 1>(xsw, wb, acc, l15, kc, oys);
    else if (clsid == 2) round_cls<1, 0>(xsw, wb, acc, l15, kc, oys);
    else                 round_cls<1, 1>(xsw, wb, acc, l15, kc, oys);
    __syncthreads();
  }

  // ---- epilogue: bias + mask fused, direct register stores ----
  const int ph = clsid >> 1, pw = clsid & 1;
  const int oy = 2 * oyq + oys, oh = 2 * oy + ph;
  const unsigned char* mrow = many + ((size_t)b * OHH + oh) * OWW + pw;
  unsigned char mb[4];
  #pragma unroll
  for (int ti = 0; ti < 4; ++ti) mb[ti] = mrow[2 * (ti * 16 + l15)];
  float* ob = out + (((size_t)(b * COUT)) * OHH + oh) * OWW + pw;
  #pragma unroll
  for (int mi = 0; mi < 8; ++mi) {
    const f32x4 bv = *(const f32x4*)(bias + mi * 16 + kc * 4);
    #pragma unroll
    for (int r = 0; r < 4; ++r) {
      const int co = mi * 16 + kc * 4 + r;
      float* orow = ob + (size_t)co * (OHH * OWW);
      #pragma unroll
      for (int ti = 0; ti < 4; ++ti)
        orow[2 * (ti * 16 + l15)] = mb[ti] ? acc[mi][ti][r] + bv[r] : 0.f;
    }
  }
}

extern "C" void kernel_launch(void* const* d_in, const int* in_sizes, int n_in,
                              void* d_out, int out_size, void* d_ws, size_t ws_size,
                              hipStream_t stream) {
  const float* x    = (const float*)d_in[0];
  const int*   mask = (const int*)d_in[1];
  const float* w    = (const float*)d_in[2];
  const float* bias = (const float*)d_in[3];
  float* out = (float*)d_out;

  // ws: many 128KB | x4 14.6MB | w3 1.23MB  (~16MB)
  unsigned char*  many = (unsigned char*)d_ws;
  unsigned short* x4   = (unsigned short*)((char*)d_ws + 131072);
  unsigned short* w3   = (unsigned short*)((char*)d_ws + 131072 +
                                           (size_t)NB * 66 * X4_IYH_B);

  pool_mask_k<<<(NB * OHH * OWW + 255) / 256, 256, 0, stream>>>(mask, many);
  xpose_k<<<NB * 66, 256, 0, stream>>>(x, x4);
  wpack_k<<<(CIN * COUT) / 256, 256, 0, stream>>>(w, w3);
  convt_mfma<<<256, 512, 0, stream>>>(x4, w3, bias, many, out);
}

// Round 10
// 76.074 us; speedup vs baseline: 1.5269x; 1.5269x over previous
//
#include <hip/hip_runtime.h>

// MyConvT: masked ConvTranspose2d, B=8, Cin=192, Cout=128, 64x64 -> 128x128,
// K=5, S=2, P=2, OP=1.  out = pooled_mask ? (convT(x,w) + bias) : 0
// Round 9: balanced waves + weights via deep LDS ring.
//   Block = 64co x 4oy x 128ow x all-4-classes; grid 256 = 1/CU; 8 waves =
//   (co-half 2) x (oy 4) — every wave runs the SAME 25-tap schedule (16 MFMA
//   per tap), so per-tap s_barrier costs only jitter. Weights: 12-slot x 8KB
//   LDS tap-ring, staged 8 taps ahead via global_load_lds, uniform counted
//   vmcnt(8) gate (never 0 mid-loop). x: 6 planes (55KB) single-buffered per
//   ci64 round. All LDS reads XOR-swizzled (verified 0-conflict pattern).

#define NB   8
#define CIN  192
#define COUT 128
#define HH   64
#define OHH  128
#define OWW  128
#define MH   132
#define MW   132

#define X4_IYH_B 27648               // bytes per (b,iyH): 3 c3 x 72 rows x 128B
#define PLANE_B  9216                // one c3 plane slice: 72 rows x 128B
#define XBUF_B   55296               // 6 planes
#define WOFF     55296
#define NSLOT    12
#define LDS_B    (XBUF_B + NSLOT * 8192)   // 153,600 <= 160K

typedef short bf16x8 __attribute__((ext_vector_type(8)));
typedef float f32x4  __attribute__((ext_vector_type(4)));
typedef float f32x2  __attribute__((ext_vector_type(2)));

static __device__ __forceinline__ unsigned short f2bf(float f) {
  union { float f; unsigned int u; } a; a.f = f;
  return (unsigned short)((a.u + 0x7fffu + ((a.u >> 16) & 1u)) >> 16);   // RNE
}

#define GLOAD_LDS16(gp, lp) __builtin_amdgcn_global_load_lds(                      \
    (const __attribute__((address_space(1))) void*)(gp),                           \
    (__attribute__((address_space(3))) void*)(lp), 16, 0, 0)

// ---------------- mask 5x5 any-pool -> byte map [B][OH][OW] ----------------
__global__ __launch_bounds__(256) void pool_mask_k(const int* __restrict__ mask,
                                                   unsigned char* __restrict__ many) {
  int idx = blockIdx.x * 256 + threadIdx.x;
  if (idx >= NB * OHH * OWW) return;
  int ow = idx & (OWW - 1);
  int oh = (idx >> 7) & (OHH - 1);
  int b  = idx >> 14;
  const int* mp = mask + (b * MH + oh) * MW + ow;
  int any = 0;
  #pragma unroll
  for (int i = 0; i < 5; ++i)
    #pragma unroll
    for (int j = 0; j < 5; ++j)
      any |= mp[i * MW + j];
  many[idx] = (any != 0) ? 1 : 0;
}

// x transpose: [b][ci][iy][ix] f32 -> x4[b][iyH 66][c3 3][row 72][ci64] bf16
// iyH = iy+1 (0,65 zero halo planes); row = ixm = ix+1 (rows 0,65 zero halo;
// rows 66..71 pad, staged but never read).
__global__ __launch_bounds__(256) void xpose_k(const float* __restrict__ x,
                                               unsigned short* __restrict__ x4) {
  const int b = blockIdx.x / 66, iyH = blockIdx.x % 66;
  const int lane = threadIdx.x & 63, wv = threadIdx.x >> 6;
  unsigned short* pl = x4 + (size_t)(b * 66 + iyH) * (X4_IYH_B / 2);

  if (iyH == 0 || iyH == 65) {                       // zero halo plane
    for (int i = threadIdx.x; i < X4_IYH_B / 16; i += 256)
      *(uint4*)(pl + i * 8) = make_uint4(0, 0, 0, 0);
    return;
  }
  const int iy = iyH - 1;
  if (threadIdx.x < 48) {                            // halo rows 0,65 per c3
    int c3 = threadIdx.x >> 4, rr = (threadIdx.x >> 3) & 1, ch = threadIdx.x & 7;
    *(uint4*)(pl + (c3 * 72 + rr * 65) * 64 + ch * 8) = make_uint4(0, 0, 0, 0);
  }
  #pragma unroll
  for (int k = 0; k < 6; ++k) {
    int ci0 = wv * 48 + k * 8;
    int c3 = ci0 >> 6, cr = ci0 & 63;
    unsigned short p[8];
    #pragma unroll
    for (int e = 0; e < 8; ++e)
      p[e] = f2bf(x[(((size_t)b * CIN + ci0 + e) * HH + iy) * HH + lane]);
    uint4 v;
    v.x = (unsigned)p[0] | ((unsigned)p[1] << 16);
    v.y = (unsigned)p[2] | ((unsigned)p[3] << 16);
    v.z = (unsigned)p[4] | ((unsigned)p[5] << 16);
    v.w = (unsigned)p[6] | ((unsigned)p[7] << 16);
    *(uint4*)(pl + ((size_t)c3 * 72 + 1 + lane) * 64 + cr) = v;
  }
}

// w repack: [ci][co][kh][kw] f32 -> w4[tap 25][cob 2][c3 3][co64][ci64] bf16
__global__ __launch_bounds__(256) void wpack_k(const float* __restrict__ w,
                                               unsigned short* __restrict__ w4) {
  int idx = blockIdx.x * 256 + threadIdx.x;          // 24576 = 192*128
  if (idx >= CIN * COUT) return;
  int ci = idx % CIN, co = idx / CIN;
  int cob = co >> 6, c = co & 63, c3 = ci >> 6, cir = ci & 63;
  const float* src = w + (size_t)(ci * COUT + co) * 25;
  #pragma unroll
  for (int tap = 0; tap < 25; ++tap)
    w4[(size_t)((tap * 2 + cob) * 3 + c3) * 4096 + c * 64 + cir] = f2bf(src[tap]);
}

// ------------------------------ main kernel --------------------------------
// grid 256: bid&7 = b (== XCD), q = bid>>3: cob = q&1, oyq = q>>1.
// 512 thr = 8 waves: cos = wv&1 (co 32-half), oyr = wv>>1 (oy row).
__global__ __launch_bounds__(512, 2) void convt_mfma(
    const unsigned short* __restrict__ x4, const unsigned short* __restrict__ w4,
    const float* __restrict__ bias, const unsigned char* __restrict__ many,
    float* __restrict__ out) {
  __shared__ char lds[LDS_B];
  // tap schedule: 9 (kk,kj) groups; bf reloaded at group starts (TNG=1)
  constexpr int TKH[25] = {0,0,1,1, 0,0,1,1, 0,1, 2,2,3,3, 2,2,3,3, 2,3, 4,4, 4,4, 4};
  constexpr int TKW[25] = {0,1,0,1, 2,3,2,3, 4,4, 0,1,0,1, 2,3,2,3, 4,4, 0,1, 2,3, 4};
  constexpr int TNG[25] = {1,0,0,0, 1,0,0,0, 1,0, 1,0,0,0, 1,0,0,0, 1,0, 1,0, 1,0, 1};

  const int tid = threadIdx.x, lane = tid & 63, wv = tid >> 6;
  const int l15 = lane & 15, kc = lane >> 4;
  const int cos = wv & 1, oyr = wv >> 1;
  const int b = blockIdx.x & 7, qq = blockIdx.x >> 3;
  const int cob = qq & 1, oyq = qq >> 1;
  const int oy0 = oyq * 4, oy = oy0 + oyr;
  // inverse-permuted source lane offset (matches read-side XOR swizzle)
  const int sswz = (lane >> 3) * 128 + (((lane & 7) ^ (lane >> 3)) << 4);

  const char* x4b = (const char*)x4 + (size_t)(b * 66 + oy0) * X4_IYH_B;
  const char* w4b = (const char*)w4 + cob * 24576;

  f32x4 acc[2][2][2][4];                 // [ph][pw][mi][ti]
  #pragma unroll
  for (int p = 0; p < 2; ++p)
    #pragma unroll
    for (int q2 = 0; q2 < 2; ++q2)
      #pragma unroll
      for (int i = 0; i < 2; ++i)
        #pragma unroll
        for (int j = 0; j < 4; ++j)
          acc[p][q2][i][j] = (f32x4){0.f, 0.f, 0.f, 0.f};

  // ---- prologue: x round 0 (54 chunks) + w taps 0..7 ----
  #pragma unroll
  for (int j = 0; j < 7; ++j) {
    int qc = wv + 8 * j;
    if (qc < 54) {
      int p = qc / 9, ch = qc % 9;
      GLOAD_LDS16(x4b + (size_t)p * X4_IYH_B + ch * 1024 + sswz,
                  lds + p * PLANE_B + ch * 1024 + lane * 16);
    }
  }
  #pragma unroll
  for (int g = 0; g < 8; ++g)
    GLOAD_LDS16(w4b + (size_t)(TKH[g] * 5 + TKW[g]) * 49152 + wv * 1024 + sswz,
                lds + WOFF + g * 8192 + wv * 1024 + lane * 16);
  asm volatile("s_waitcnt vmcnt(0)" ::: "memory");
  __builtin_amdgcn_s_barrier();

  bf16x8 bfr[2][4], afr[2][2];
  #pragma unroll 1
  for (int c3 = 0; c3 < 3; ++c3) {
    #pragma unroll
    for (int t = 0; t < 25; ++t) {
      // stage tap g+8 into ring (slot (g+8)%12; 25 % 12 == 1 => slot = t+8+c3 mod 12)
      if (c3 < 2 || t < 17) {
        const int tn = (t < 17) ? t + 8 : t - 17;
        const int rn = (t < 17) ? c3 : c3 + 1;
        int s8 = t + 8 + c3; if (s8 >= NSLOT) s8 -= NSLOT; if (s8 >= NSLOT) s8 -= NSLOT;
        GLOAD_LDS16(w4b + (size_t)(TKH[tn] * 5 + TKW[tn]) * 49152 + rn * 8192
                        + wv * 1024 + sswz,
                    lds + WOFF + s8 * 8192 + wv * 1024 + lane * 16);
      }
      asm volatile("s_waitcnt vmcnt(8)" ::: "memory");   // own chunk of tap t landed
      __builtin_amdgcn_s_barrier();                      // everyone's chunks landed
      if (TNG[t]) {                     // new (kk,kj) group: reload bf (8 reads)
        const int kj = TKW[t] >> 1, kk = TKH[t] >> 1;
        const int p = oyr + 2 - kk;
        #pragma unroll
        for (int k2 = 0; k2 < 2; ++k2)
          #pragma unroll
          for (int ti = 0; ti < 4; ++ti) {
            const int row = ti * 16 + l15 + 2 - kj;
            bfr[k2][ti] = *(const bf16x8*)(lds + p * PLANE_B + row * 128 +
                                           (((k2 * 4 + kc) ^ (row & 7)) << 4));
          }
      }
      int sl = t + c3; if (sl >= NSLOT) sl -= NSLOT; if (sl >= NSLOT) sl -= NSLOT;
      const char* ws = lds + WOFF + sl * 8192;
      #pragma unroll
      for (int k2 = 0; k2 < 2; ++k2)
        #pragma unroll
        for (int mi = 0; mi < 2; ++mi) {
          const int row = cos * 32 + mi * 16 + l15;
          afr[k2][mi] = *(const bf16x8*)(ws + row * 128 +
                                         (((k2 * 4 + kc) ^ (l15 & 7)) << 4));
        }
      const int ph = TKH[t] & 1, pw = TKW[t] & 1;
      #pragma unroll
      for (int k2 = 0; k2 < 2; ++k2)
        #pragma unroll
        for (int mi = 0; mi < 2; ++mi)
          #pragma unroll
          for (int ti = 0; ti < 4; ++ti)
            acc[ph][pw][mi][ti] = __builtin_amdgcn_mfma_f32_16x16x32_bf16(
                afr[k2][mi], bfr[k2][ti], acc[ph][pw][mi][ti], 0, 0, 0);
    }
    if (c3 < 2) {                       // round boundary: restage x planes
      __builtin_amdgcn_s_barrier();     // all waves done reading xbuf
      #pragma unroll
      for (int j = 0; j < 7; ++j) {
        int qc = wv + 8 * j;
        if (qc < 54) {
          int p = qc / 9, ch = qc % 9;
          GLOAD_LDS16(x4b + (size_t)p * X4_IYH_B + (c3 + 1) * PLANE_B + ch * 1024 + sswz,
                      lds + p * PLANE_B + ch * 1024 + lane * 16);
        }
      }
      asm volatile("s_waitcnt vmcnt(0)" ::: "memory");
      __builtin_amdgcn_s_barrier();
    }
  }

  // ---- epilogue: bias + mask fused, fully-coalesced f32x2 stores ----
  const int cobase = cob * 64 + cos * 32;
  #pragma unroll
  for (int mi = 0; mi < 2; ++mi) {
    const f32x4 bv = *(const f32x4*)(bias + cobase + mi * 16 + kc * 4);
    #pragma unroll
    for (int ph = 0; ph < 2; ++ph) {
      const int oh = 2 * oy + ph;
      const unsigned char* mrow = many + ((size_t)b * OHH + oh) * OWW;
      #pragma unroll
      for (int ti = 0; ti < 4; ++ti) {
        const int ow0 = 2 * (ti * 16 + l15);
        const unsigned short m2 = *(const unsigned short*)(mrow + ow0);
        #pragma unroll
        for (int r = 0; r < 4; ++r) {
          const int co = cobase + mi * 16 + kc * 4 + r;
          f32x2 v;
          v.x = (m2 & 0x00FFu) ? acc[ph][0][mi][ti][r] + bv[r] : 0.f;
          v.y = (m2 & 0xFF00u) ? acc[ph][1][mi][ti][r] + bv[r] : 0.f;
          *(f32x2*)(out + (((size_t)(b * COUT + co)) * OHH + oh) * OWW + ow0) = v;
        }
      }
    }
  }
}

extern "C" void kernel_launch(void* const* d_in, const int* in_sizes, int n_in,
                              void* d_out, int out_size, void* d_ws, size_t ws_size,
                              hipStream_t stream) {
  const float* x    = (const float*)d_in[0];
  const int*   mask = (const int*)d_in[1];
  const float* w    = (const float*)d_in[2];
  const float* bias = (const float*)d_in[3];
  float* out = (float*)d_out;

  // ws: many 128KB | x4 14.6MB | w4 1.23MB  (~16MB)
  unsigned char*  many = (unsigned char*)d_ws;
  unsigned short* x4   = (unsigned short*)((char*)d_ws + 131072);
  unsigned short* w4   = (unsigned short*)((char*)d_ws + 131072 +
                                           (size_t)NB * 66 * X4_IYH_B);

  pool_mask_k<<<(NB * OHH * OWW + 255) / 256, 256, 0, stream>>>(mask, many);
  xpose_k<<<NB * 66, 256, 0, stream>>>(x, x4);
  wpack_k<<<(CIN * COUT + 255) / 256, 256, 0, stream>>>(w, w4);
  convt_mfma<<<256, 512, 0, stream>>>(x4, w4, bias, many, out);
}

// Round 11
// 62.988 us; speedup vs baseline: 1.8441x; 1.2078x over previous
//
#include <hip/hip_runtime.h>

// MyConvT: masked ConvTranspose2d, B=8, Cin=192, Cout=128, 64x64 -> 128x128,
// K=5, S=2, P=2, OP=1.  out = pooled_mask ? (convT(x,w) + bias) : 0
// Round 10: r9 schedule at 2 blocks/CU. Block = 256 thr = 4 waves (cos x oyr),
// 64co x 2oy x 128ow x all-4-classes. x: 4 planes (36KB) single-buffered per
// ci64 round. w: 5-slot x 8KB LDS tap-ring, staged 3 ahead, steady vmcnt(6)
// (tail 4/2/0; round boundary 0). LDS 77,824 B => 2 blocks/CU; sync overhead
// of one block overlaps the other's MFMA (m114). setprio(1) around MFMA (T5).

#define NB   8
#define CIN  192
#define COUT 128
#define HH   64
#define OHH  128
#define OWW  128
#define MH   132
#define MW   132

#define X4_IYH_B 27648               // bytes per (b,iyH): 3 c3 x 72 rows x 128B
#define PLANE_B  9216                // one c3 plane slice: 72 rows x 128B
#define XBUF_B   36864               // 4 planes
#define WOFF     36864
#define NSLOT    5
#define LDS_B    (XBUF_B + NSLOT * 8192)   // 77,824 <= 81,920 (2 blocks/CU)

typedef short bf16x8 __attribute__((ext_vector_type(8)));
typedef float f32x4  __attribute__((ext_vector_type(4)));
typedef float f32x2  __attribute__((ext_vector_type(2)));

static __device__ __forceinline__ unsigned short f2bf(float f) {
  union { float f; unsigned int u; } a; a.f = f;
  return (unsigned short)((a.u + 0x7fffu + ((a.u >> 16) & 1u)) >> 16);   // RNE
}

#define GLOAD_LDS16(gp, lp) __builtin_amdgcn_global_load_lds(                      \
    (const __attribute__((address_space(1))) void*)(gp),                           \
    (__attribute__((address_space(3))) void*)(lp), 16, 0, 0)

// ---------------- mask 5x5 any-pool -> byte map [B][OH][OW] ----------------
__global__ __launch_bounds__(256) void pool_mask_k(const int* __restrict__ mask,
                                                   unsigned char* __restrict__ many) {
  int idx = blockIdx.x * 256 + threadIdx.x;
  if (idx >= NB * OHH * OWW) return;
  int ow = idx & (OWW - 1);
  int oh = (idx >> 7) & (OHH - 1);
  int b  = idx >> 14;
  const int* mp = mask + (b * MH + oh) * MW + ow;
  int any = 0;
  #pragma unroll
  for (int i = 0; i < 5; ++i)
    #pragma unroll
    for (int j = 0; j < 5; ++j)
      any |= mp[i * MW + j];
  many[idx] = (any != 0) ? 1 : 0;
}

// x transpose: [b][ci][iy][ix] f32 -> x4[b][iyH 66][c3 3][row 72][ci64] bf16
__global__ __launch_bounds__(256) void xpose_k(const float* __restrict__ x,
                                               unsigned short* __restrict__ x4) {
  const int b = blockIdx.x / 66, iyH = blockIdx.x % 66;
  const int lane = threadIdx.x & 63, wv = threadIdx.x >> 6;
  unsigned short* pl = x4 + (size_t)(b * 66 + iyH) * (X4_IYH_B / 2);

  if (iyH == 0 || iyH == 65) {                       // zero halo plane
    for (int i = threadIdx.x; i < X4_IYH_B / 16; i += 256)
      *(uint4*)(pl + i * 8) = make_uint4(0, 0, 0, 0);
    return;
  }
  const int iy = iyH - 1;
  if (threadIdx.x < 48) {                            // halo rows 0,65 per c3
    int c3 = threadIdx.x >> 4, rr = (threadIdx.x >> 3) & 1, ch = threadIdx.x & 7;
    *(uint4*)(pl + (c3 * 72 + rr * 65) * 64 + ch * 8) = make_uint4(0, 0, 0, 0);
  }
  #pragma unroll
  for (int k = 0; k < 6; ++k) {
    int ci0 = wv * 48 + k * 8;
    int c3 = ci0 >> 6, cr = ci0 & 63;
    unsigned short p[8];
    #pragma unroll
    for (int e = 0; e < 8; ++e)
      p[e] = f2bf(x[(((size_t)b * CIN + ci0 + e) * HH + iy) * HH + lane]);
    uint4 v;
    v.x = (unsigned)p[0] | ((unsigned)p[1] << 16);
    v.y = (unsigned)p[2] | ((unsigned)p[3] << 16);
    v.z = (unsigned)p[4] | ((unsigned)p[5] << 16);
    v.w = (unsigned)p[6] | ((unsigned)p[7] << 16);
    *(uint4*)(pl + ((size_t)c3 * 72 + 1 + lane) * 64 + cr) = v;
  }
}

// w repack: [ci][co][kh][kw] f32 -> w4[tap 25][cob 2][c3 3][co64][ci64] bf16
__global__ __launch_bounds__(256) void wpack_k(const float* __restrict__ w,
                                               unsigned short* __restrict__ w4) {
  int idx = blockIdx.x * 256 + threadIdx.x;          // 24576 = 192*128
  if (idx >= CIN * COUT) return;
  int ci = idx % CIN, co = idx / CIN;
  int cob = co >> 6, c = co & 63, c3 = ci >> 6, cir = ci & 63;
  const float* src = w + (size_t)(ci * COUT + co) * 25;
  #pragma unroll
  for (int tap = 0; tap < 25; ++tap)
    w4[(size_t)((tap * 2 + cob) * 3 + c3) * 4096 + c * 64 + cir] = f2bf(src[tap]);
}

// ------------------------------ main kernel --------------------------------
// grid 512: bid&7 = b (== XCD); qq = bid>>3: cob = qq&1, oyq = qq>>1 (0..31).
// 256 thr = 4 waves: cos = wv&1 (co 32-half), oyr = wv>>1 (oy row of pair).
__global__ __launch_bounds__(256, 2) void convt_mfma(
    const unsigned short* __restrict__ x4, const unsigned short* __restrict__ w4,
    const float* __restrict__ bias, const unsigned char* __restrict__ many,
    float* __restrict__ out) {
  __shared__ char lds[LDS_B];
  // tap schedule: 9 (kk,kj) groups; bf reloaded at group starts (TNG=1)
  constexpr int TKH[25] = {0,0,1,1, 0,0,1,1, 0,1, 2,2,3,3, 2,2,3,3, 2,3, 4,4, 4,4, 4};
  constexpr int TKW[25] = {0,1,0,1, 2,3,2,3, 4,4, 0,1,0,1, 2,3,2,3, 4,4, 0,1, 2,3, 4};
  constexpr int TNG[25] = {1,0,0,0, 1,0,0,0, 1,0, 1,0,0,0, 1,0,0,0, 1,0, 1,0, 1,0, 1};

  const int tid = threadIdx.x, lane = tid & 63, wv = tid >> 6;
  const int l15 = lane & 15, kc = lane >> 4;
  const int cos = wv & 1, oyr = wv >> 1;
  const int b = blockIdx.x & 7, qq = blockIdx.x >> 3;
  const int cob = qq & 1, oyq = qq >> 1;
  const int oy0 = oyq * 2, oy = oy0 + oyr;
  // inverse-permuted source lane offset (matches read-side XOR swizzle)
  const int sswz = (lane >> 3) * 128 + (((lane & 7) ^ (lane >> 3)) << 4);

  const char* x4b = (const char*)x4 + (size_t)(b * 66 + oy0) * X4_IYH_B;
  const char* w4b = (const char*)w4 + cob * 24576;

  f32x4 acc[2][2][2][4];                 // [ph][pw][mi][ti]
  #pragma unroll
  for (int p = 0; p < 2; ++p)
    #pragma unroll
    for (int q2 = 0; q2 < 2; ++q2)
      #pragma unroll
      for (int i = 0; i < 2; ++i)
        #pragma unroll
        for (int j = 0; j < 4; ++j)
          acc[p][q2][i][j] = (f32x4){0.f, 0.f, 0.f, 0.f};

  auto stage_x = [&](int c3) {
    #pragma unroll
    for (int j = 0; j < 9; ++j) {
      int qc = wv + 4 * j;                           // 36 chunks of 1KB
      int p = qc / 9, ch = qc % 9;
      GLOAD_LDS16(x4b + (size_t)p * X4_IYH_B + c3 * PLANE_B + ch * 1024 + sswz,
                  lds + p * PLANE_B + ch * 1024 + lane * 16);
    }
  };
  auto stage_w = [&](int tap, int c3, int slot) {     // 2 x 1KB per wave
    const char* s = w4b + (size_t)(TKH[tap] * 5 + TKW[tap]) * 49152 + c3 * 8192
                    + wv * 2048 + sswz;
    char* d = lds + WOFF + slot * 8192 + wv * 2048 + lane * 16;
    GLOAD_LDS16(s, d);
    GLOAD_LDS16(s + 1024, d + 1024);
  };

  // ---- prologue: x round 0 + w taps 0,1,2 ----
  stage_x(0);
  stage_w(0, 0, 0);
  stage_w(1, 0, 1);
  stage_w(2, 0, 2);
  asm volatile("s_waitcnt vmcnt(4)" ::: "memory");    // x + w0 done; w1,w2 in flight
  __builtin_amdgcn_s_barrier();

  bf16x8 bfr[2][4], afr[2][2];
  #pragma unroll 1
  for (int c3 = 0; c3 < 3; ++c3) {
    #pragma unroll
    for (int t = 0; t < 25; ++t) {
      // stage step s+3's tap into ring slot (t+3)%5
      if (c3 < 2 || t < 22) {
        const int tn = (t + 3 < 25) ? t + 3 : t - 22;
        const int cn = (t + 3 < 25) ? c3 : c3 + 1;
        stage_w(tn, cn, (t + 3) % 5);
      }
      // counted gate: current tap's loads landed (never 0 mid-loop)
      if (c3 == 2 && t >= 22) {
        if (t == 22)      asm volatile("s_waitcnt vmcnt(4)" ::: "memory");
        else if (t == 23) asm volatile("s_waitcnt vmcnt(2)" ::: "memory");
        else              asm volatile("s_waitcnt vmcnt(0)" ::: "memory");
      } else {
        asm volatile("s_waitcnt vmcnt(6)" ::: "memory");
      }
      __builtin_amdgcn_s_barrier();
      if (TNG[t]) {                     // new (kk,kj) group: reload bf
        const int kj = TKW[t] >> 1, kk = TKH[t] >> 1;
        const int p = oyr + 2 - kk;
        #pragma unroll
        for (int k2 = 0; k2 < 2; ++k2)
          #pragma unroll
          for (int ti = 0; ti < 4; ++ti) {
            const int row = ti * 16 + l15 + 2 - kj;
            bfr[k2][ti] = *(const bf16x8*)(lds + p * PLANE_B + row * 128 +
                                           (((k2 * 4 + kc) ^ (row & 7)) << 4));
          }
      }
      const char* ws = lds + WOFF + (t % 5) * 8192;
      #pragma unroll
      for (int k2 = 0; k2 < 2; ++k2)
        #pragma unroll
        for (int mi = 0; mi < 2; ++mi) {
          const int row = cos * 32 + mi * 16 + l15;
          afr[k2][mi] = *(const bf16x8*)(ws + row * 128 +
                                         (((k2 * 4 + kc) ^ (l15 & 7)) << 4));
        }
      const int ph = TKH[t] & 1, pw = TKW[t] & 1;
      __builtin_amdgcn_s_setprio(1);
      #pragma unroll
      for (int k2 = 0; k2 < 2; ++k2)
        #pragma unroll
        for (int mi = 0; mi < 2; ++mi)
          #pragma unroll
          for (int ti = 0; ti < 4; ++ti)
            acc[ph][pw][mi][ti] = __builtin_amdgcn_mfma_f32_16x16x32_bf16(
                afr[k2][mi], bfr[k2][ti], acc[ph][pw][mi][ti], 0, 0, 0);
      __builtin_amdgcn_s_setprio(0);
    }
    if (c3 < 2) {                       // round boundary: restage x planes
      __builtin_amdgcn_s_barrier();     // all waves done reading xbuf
      stage_x(c3 + 1);
      asm volatile("s_waitcnt vmcnt(0)" ::: "memory");
      __builtin_amdgcn_s_barrier();
    }
  }

  // ---- epilogue: bias + mask fused, fully-coalesced f32x2 stores ----
  const int cobase = cob * 64 + cos * 32;
  #pragma unroll
  for (int mi = 0; mi < 2; ++mi) {
    const f32x4 bv = *(const f32x4*)(bias + cobase + mi * 16 + kc * 4);
    #pragma unroll
    for (int ph = 0; ph < 2; ++ph) {
      const int oh = 2 * oy + ph;
      const unsigned char* mrow = many + ((size_t)b * OHH + oh) * OWW;
      #pragma unroll
      for (int ti = 0; ti < 4; ++ti) {
        const int ow0 = 2 * (ti * 16 + l15);
        const unsigned short m2 = *(const unsigned short*)(mrow + ow0);
        #pragma unroll
        for (int r = 0; r < 4; ++r) {
          const int co = cobase + mi * 16 + kc * 4 + r;
          f32x2 v;
          v.x = (m2 & 0x00FFu) ? acc[ph][0][mi][ti][r] + bv[r] : 0.f;
          v.y = (m2 & 0xFF00u) ? acc[ph][1][mi][ti][r] + bv[r] : 0.f;
          *(f32x2*)(out + (((size_t)(b * COUT + co)) * OHH + oh) * OWW + ow0) = v;
        }
      }
    }
  }
}

extern "C" void kernel_launch(void* const* d_in, const int* in_sizes, int n_in,
                              void* d_out, int out_size, void* d_ws, size_t ws_size,
                              hipStream_t stream) {
  const float* x    = (const float*)d_in[0];
  const int*   mask = (const int*)d_in[1];
  const float* w    = (const float*)d_in[2];
  const float* bias = (const float*)d_in[3];
  float* out = (float*)d_out;

  // ws: many 128KB | x4 14.6MB | w4 1.23MB  (~16MB)
  unsigned char*  many = (unsigned char*)d_ws;
  unsigned short* x4   = (unsigned short*)((char*)d_ws + 131072);
  unsigned short* w4   = (unsigned short*)((char*)d_ws + 131072 +
                                           (size_t)NB * 66 * X4_IYH_B);

  pool_mask_k<<<(NB * OHH * OWW + 255) / 256, 256, 0, stream>>>(mask, many);
  xpose_k<<<NB * 66, 256, 0, stream>>>(x, x4);
  wpack_k<<<(CIN * COUT + 255) / 256, 256, 0, stream>>>(w, w4);
  convt_mfma<<<512, 256, 0, stream>>>(x4, w4, bias, many, out);
}

// Round 13
// 61.084 us; speedup vs baseline: 1.9016x; 1.0312x over previous
//
#include <hip/hip_runtime.h>

// MyConvT: masked ConvTranspose2d, B=8, Cin=192, Cout=128, 64x64 -> 128x128,
// K=5, S=2, P=2, OP=1.  out = pooled_mask ? (convT(x,w) + bias) : 0
// Round 12 = r11 with the prologue staging bug fixed: stage_w takes a TAPID
// (kh*5+kw); flat taps 0,1,2 = (0,0),(0,1),(1,0) = tapids {0,1,5} (r11
// wrongly staged tapid 2). Structure: fused prep (1 kernel) + convt at
// 2 blocks/CU, 5-slot w-ring staged 3 ahead w/ counted vmcnt, bf (x-frag)
// double-buffer prefetched during prior group's MFMA burst.

#define NB   8
#define CIN  192
#define COUT 128
#define HH   64
#define OHH  128
#define OWW  128
#define MH   132
#define MW   132

#define X4_IYH_B 27648               // bytes per (b,iyH): 3 c3 x 72 rows x 128B
#define PLANE_B  9216                // one c3 plane slice: 72 rows x 128B
#define XBUF_B   36864               // 4 planes
#define WOFF     36864
#define NSLOT    5
#define LDS_B    (XBUF_B + NSLOT * 8192)   // 77,824 <= 81,920 (2 blocks/CU)

typedef short bf16x8 __attribute__((ext_vector_type(8)));
typedef float f32x4  __attribute__((ext_vector_type(4)));
typedef float f32x2  __attribute__((ext_vector_type(2)));

static __device__ __forceinline__ unsigned short f2bf(float f) {
  union { float f; unsigned int u; } a; a.f = f;
  return (unsigned short)((a.u + 0x7fffu + ((a.u >> 16) & 1u)) >> 16);   // RNE
}

#define GLOAD_LDS16(gp, lp) __builtin_amdgcn_global_load_lds(                      \
    (const __attribute__((address_space(1))) void*)(gp),                           \
    (__attribute__((address_space(3))) void*)(lp), 16, 0, 0)

// ---------------- fused prep: xpose (528) | wpack (96) | pool (128) --------
__global__ __launch_bounds__(256) void prep_k(
    const float* __restrict__ x, const int* __restrict__ mask,
    const float* __restrict__ w, unsigned short* __restrict__ x4,
    unsigned short* __restrict__ w4, unsigned char* __restrict__ many) {
  const int bid = blockIdx.x, tid = threadIdx.x;

  if (bid < 528) {                                   // ---- xpose ----
    const int b = bid / 66, iyH = bid % 66;
    const int lane = tid & 63, wv = tid >> 6;
    unsigned short* pl = x4 + (size_t)(b * 66 + iyH) * (X4_IYH_B / 2);

    if (iyH == 0 || iyH == 65) {                     // zero halo plane
      for (int i = tid; i < X4_IYH_B / 16; i += 256)
        *(uint4*)(pl + i * 8) = make_uint4(0, 0, 0, 0);
      return;
    }
    const int iy = iyH - 1;
    if (tid < 48) {                                  // halo rows 0,65 per c3
      int c3 = tid >> 4, rr = (tid >> 3) & 1, ch = tid & 7;
      *(uint4*)(pl + (c3 * 72 + rr * 65) * 64 + ch * 8) = make_uint4(0, 0, 0, 0);
    }
    #pragma unroll
    for (int k = 0; k < 6; ++k) {
      int ci0 = wv * 48 + k * 8;
      int c3 = ci0 >> 6, cr = ci0 & 63;
      unsigned short p[8];
      #pragma unroll
      for (int e = 0; e < 8; ++e)
        p[e] = f2bf(x[(((size_t)b * CIN + ci0 + e) * HH + iy) * HH + lane]);
      uint4 v;
      v.x = (unsigned)p[0] | ((unsigned)p[1] << 16);
      v.y = (unsigned)p[2] | ((unsigned)p[3] << 16);
      v.z = (unsigned)p[4] | ((unsigned)p[5] << 16);
      v.w = (unsigned)p[6] | ((unsigned)p[7] << 16);
      *(uint4*)(pl + ((size_t)c3 * 72 + 1 + lane) * 64 + cr) = v;
    }
  } else if (bid < 624) {                            // ---- wpack ----
    int idx = (bid - 528) * 256 + tid;               // 0..24575
    int ci = idx % CIN, co = idx / CIN;
    int cob = co >> 6, c = co & 63, c3 = ci >> 6, cir = ci & 63;
    const float* src = w + (size_t)(ci * COUT + co) * 25;
    #pragma unroll
    for (int tap = 0; tap < 25; ++tap)
      w4[(size_t)((tap * 2 + cob) * 3 + c3) * 4096 + c * 64 + cir] = f2bf(src[tap]);
  } else {                                           // ---- pool (4 ow/thr) ----
    int g = (bid - 624) * 256 + tid;                 // 0..32767
    int owq = g & 31, oh = (g >> 5) & 127, b = g >> 12;
    const int* mp = mask + (b * MH + oh) * MW + owq * 4;
    int a0 = 0, a1 = 0, a2 = 0, a3 = 0;
    #pragma unroll
    for (int i = 0; i < 5; ++i) {
      int4 u = *(const int4*)(mp + i * MW);
      int4 v = *(const int4*)(mp + i * MW + 4);
      int c = u.z | u.w | v.x;                       // cols +2,+3,+4
      a0 |= u.x | u.y | c;
      a1 |= u.y | c | v.y;
      a2 |= c | v.y | v.z;
      a3 |= u.w | v.x | v.y | v.z | v.w;
    }
    *(uchar4*)(many + ((size_t)b * OHH + oh) * OWW + owq * 4) =
        make_uchar4(a0 ? 1 : 0, a1 ? 1 : 0, a2 ? 1 : 0, a3 ? 1 : 0);
  }
}

// ------------------------------ main kernel --------------------------------
// tap flat order (matches the 5-slot ring staging):
// g0:(0,0)(0,1)(1,0)(1,1) g1:(0,2)(0,3)(1,2)(1,3) g2:(0,4)(1,4)
// g3:(2,0)(2,1)(3,0)(3,1) g4:(2,2)(2,3)(3,2)(3,3) g5:(2,4)(3,4)
// g6:(4,0)(4,1) g7:(4,2)(4,3) g8:(4,4)
__constant__ const int TKH[25] = {0,0,1,1, 0,0,1,1, 0,1, 2,2,3,3, 2,2,3,3, 2,3, 4,4, 4,4, 4};
__constant__ const int TKW[25] = {0,1,0,1, 2,3,2,3, 4,4, 0,1,0,1, 2,3,2,3, 4,4, 0,1, 2,3, 4};

#define BF_LOAD(S, KK, KJ)                                                     \
  { const int p_ = oyr + 2 - (KK);                                             \
    _Pragma("unroll") for (int k2 = 0; k2 < 2; ++k2)                           \
      _Pragma("unroll") for (int ti = 0; ti < 4; ++ti) {                       \
        const int row_ = ti * 16 + l15 + 2 - (KJ);                             \
        bfr[S][k2][ti] = *(const bf16x8*)(lds + p_ * PLANE_B + row_ * 128 +    \
                                          (((k2 * 4 + kc) ^ (row_ & 7)) << 4)); } }

#define AF_LOAD(T)                                                             \
  { const char* ws_ = lds + WOFF + ((T) % 5) * 8192;                           \
    _Pragma("unroll") for (int k2 = 0; k2 < 2; ++k2)                           \
      _Pragma("unroll") for (int mi = 0; mi < 2; ++mi) {                       \
        const int row_ = cos * 32 + mi * 16 + l15;                             \
        afr[k2][mi] = *(const bf16x8*)(ws_ + row_ * 128 +                      \
                                       (((k2 * 4 + kc) ^ (l15 & 7)) << 4)); } }

#define SG(T)                                                                  \
  { if (c3 < 2 || (T) < 22) {                                                  \
      const int tn_ = ((T) + 3 < 25) ? (T) + 3 : (T) - 22;                     \
      const int cn_ = ((T) + 3 < 25) ? c3 : c3 + 1;                            \
      stage_w(TKH[tn_] * 5 + TKW[tn_], cn_, ((T) + 3) % 5);                    \
    }                                                                          \
    if (c3 == 2 && (T) >= 22) {                                                \
      if ((T) == 22)      asm volatile("s_waitcnt vmcnt(4)" ::: "memory");     \
      else if ((T) == 23) asm volatile("s_waitcnt vmcnt(2)" ::: "memory");     \
      else                asm volatile("s_waitcnt vmcnt(0)" ::: "memory");     \
    } else {                                                                   \
      asm volatile("s_waitcnt vmcnt(6)" ::: "memory");                         \
    }                                                                          \
    __builtin_amdgcn_s_barrier(); }

#define MM(S, PH_, PW_)                                                        \
  { __builtin_amdgcn_s_setprio(1);                                             \
    _Pragma("unroll") for (int k2 = 0; k2 < 2; ++k2)                           \
      _Pragma("unroll") for (int mi = 0; mi < 2; ++mi)                         \
        _Pragma("unroll") for (int ti = 0; ti < 4; ++ti)                       \
          acc[PH_][PW_][mi][ti] = __builtin_amdgcn_mfma_f32_16x16x32_bf16(     \
              afr[k2][mi], bfr[S][k2][ti], acc[PH_][PW_][mi][ti], 0, 0, 0);    \
    __builtin_amdgcn_s_setprio(0); }

// TAP: stage+gate+barrier, af read, optional bf-prefetch of next group, MFMA
#define TAP(T, PH_, PW_, S)        { SG(T) AF_LOAD(T) MM(S, PH_, PW_) }
#define TAPP(T, PH_, PW_, S, KK, KJ) \
  { SG(T) AF_LOAD(T) BF_LOAD((S) ^ 1, KK, KJ) MM(S, PH_, PW_) }

// grid 512: bid&7 = b (== XCD); qq = bid>>3: cob = qq&1, oyq = qq>>1 (0..31).
// 256 thr = 4 waves: cos = wv&1 (co 32-half), oyr = wv>>1 (oy row of pair).
__global__ __launch_bounds__(256, 2) void convt_mfma(
    const unsigned short* __restrict__ x4, const unsigned short* __restrict__ w4,
    const float* __restrict__ bias, const unsigned char* __restrict__ many,
    float* __restrict__ out) {
  __shared__ __align__(16) char lds[LDS_B];

  const int tid = threadIdx.x, lane = tid & 63, wv = tid >> 6;
  const int l15 = lane & 15, kc = lane >> 4;
  const int cos = wv & 1, oyr = wv >> 1;
  const int b = blockIdx.x & 7, qq = blockIdx.x >> 3;
  const int cob = qq & 1, oyq = qq >> 1;
  const int oy0 = oyq * 2, oy = oy0 + oyr;
  // inverse-permuted source lane offset (matches read-side XOR swizzle)
  const int sswz = (lane >> 3) * 128 + (((lane & 7) ^ (lane >> 3)) << 4);

  const char* x4b = (const char*)x4 + (size_t)(b * 66 + oy0) * X4_IYH_B;
  const char* w4b = (const char*)w4 + cob * 24576;

  f32x4 acc[2][2][2][4];                 // [ph][pw][mi][ti]
  #pragma unroll
  for (int p = 0; p < 2; ++p)
    #pragma unroll
    for (int q2 = 0; q2 < 2; ++q2)
      #pragma unroll
      for (int i = 0; i < 2; ++i)
        #pragma unroll
        for (int j = 0; j < 4; ++j)
          acc[p][q2][i][j] = (f32x4){0.f, 0.f, 0.f, 0.f};

  auto stage_x = [&](int c3) {
    #pragma unroll
    for (int j = 0; j < 9; ++j) {
      int qc = wv + 4 * j;                           // 36 chunks of 1KB
      int p = qc / 9, ch = qc % 9;
      GLOAD_LDS16(x4b + (size_t)p * X4_IYH_B + c3 * PLANE_B + ch * 1024 + sswz,
                  lds + p * PLANE_B + ch * 1024 + lane * 16);
    }
  };
  auto stage_w = [&](int tapid, int c3n, int slot) { // 2 x 1KB per wave
    const char* s = w4b + (size_t)tapid * 49152 + c3n * 8192 + wv * 2048 + sswz;
    char* d = lds + WOFF + slot * 8192 + wv * 2048 + lane * 16;
    GLOAD_LDS16(s, d);
    GLOAD_LDS16(s + 1024, d + 1024);
  };

  // ---- prologue: x round 0 + flat taps 0,1,2 = tapids 0,1,5 ----
  stage_x(0);
  stage_w(0, 0, 0);                    // flat 0 = (0,0)
  stage_w(1, 0, 1);                    // flat 1 = (0,1)
  stage_w(5, 0, 2);                    // flat 2 = (1,0) -> tapid 5  [r11 bug]
  asm volatile("s_waitcnt vmcnt(4)" ::: "memory");    // x + w0 done; w1,w2 in flight
  __builtin_amdgcn_s_barrier();

  bf16x8 bfr[2][2][4], afr[2][2];
  #pragma unroll 1
  for (int c3 = 0; c3 < 3; ++c3) {
    BF_LOAD(0, 0, 0)                    // group 0 (kk=0,kj=0) into set 0
    TAP (0,  0, 0, 0) TAP (1,  0, 1, 0) TAP (2,  1, 0, 0)
    TAPP(3,  1, 1, 0, 0, 1)             // -> g1 (kk0,kj1) into set 1
    TAP (4,  0, 0, 1) TAP (5,  0, 1, 1) TAP (6,  1, 0, 1)
    TAPP(7,  1, 1, 1, 0, 2)             // -> g2 (kk0,kj2) into set 0
    TAP (8,  0, 0, 0)
    TAPP(9,  1, 0, 0, 1, 0)             // -> g3 (kk1,kj0) into set 1
    TAP (10, 0, 0, 1) TAP (11, 0, 1, 1) TAP (12, 1, 0, 1)
    TAPP(13, 1, 1, 1, 1, 1)             // -> g4 (kk1,kj1) into set 0
    TAP (14, 0, 0, 0) TAP (15, 0, 1, 0) TAP (16, 1, 0, 0)
    TAPP(17, 1, 1, 0, 1, 2)             // -> g5 (kk1,kj2) into set 1
    TAP (18, 0, 0, 1)
    TAPP(19, 1, 0, 1, 2, 0)             // -> g6 (kk2,kj0) into set 0
    TAP (20, 0, 0, 0)
    TAPP(21, 0, 1, 0, 2, 1)             // -> g7 (kk2,kj1) into set 1
    TAP (22, 0, 0, 1)
    TAPP(23, 0, 1, 1, 2, 2)             // -> g8 (kk2,kj2) into set 0
    TAP (24, 0, 0, 0)
    if (c3 < 2) {                       // round boundary: restage x planes
      __builtin_amdgcn_s_barrier();     // all waves done reading xbuf
      stage_x(c3 + 1);
      asm volatile("s_waitcnt vmcnt(0)" ::: "memory");
      __builtin_amdgcn_s_barrier();
    }
  }

  // ---- epilogue: bias + mask fused, fully-coalesced f32x2 stores ----
  const int cobase = cob * 64 + cos * 32;
  #pragma unroll
  for (int mi = 0; mi < 2; ++mi) {
    const f32x4 bv = *(const f32x4*)(bias + cobase + mi * 16 + kc * 4);
    #pragma unroll
    for (int ph = 0; ph < 2; ++ph) {
      const int oh = 2 * oy + ph;
      const unsigned char* mrow = many + ((size_t)b * OHH + oh) * OWW;
      #pragma unroll
      for (int ti = 0; ti < 4; ++ti) {
        const int ow0 = 2 * (ti * 16 + l15);
        const unsigned short m2 = *(const unsigned short*)(mrow + ow0);
        #pragma unroll
        for (int r = 0; r < 4; ++r) {
          const int co = cobase + mi * 16 + kc * 4 + r;
          f32x2 v;
          v.x = (m2 & 0x00FFu) ? acc[ph][0][mi][ti][r] + bv[r] : 0.f;
          v.y = (m2 & 0xFF00u) ? acc[ph][1][mi][ti][r] + bv[r] : 0.f;
          *(f32x2*)(out + (((size_t)(b * COUT + co)) * OHH + oh) * OWW + ow0) = v;
        }
      }
    }
  }
}

extern "C" void kernel_launch(void* const* d_in, const int* in_sizes, int n_in,
                              void* d_out, int out_size, void* d_ws, size_t ws_size,
                              hipStream_t stream) {
  const float* x    = (const float*)d_in[0];
  const int*   mask = (const int*)d_in[1];
  const float* w    = (const float*)d_in[2];
  const float* bias = (const float*)d_in[3];
  float* out = (float*)d_out;

  // ws: many 128KB | x4 14.6MB | w4 1.23MB  (~16MB)
  unsigned char*  many = (unsigned char*)d_ws;
  unsigned short* x4   = (unsigned short*)((char*)d_ws + 131072);
  unsigned short* w4   = (unsigned short*)((char*)d_ws + 131072 +
                                           (size_t)NB * 66 * X4_IYH_B);

  prep_k<<<752, 256, 0, stream>>>(x, mask, w, x4, w4, many);
  convt_mfma<<<512, 256, 0, stream>>>(x4, w4, bias, many, out);
}

// Round 14
// 55.124 us; speedup vs baseline: 2.1072x; 1.1081x over previous
//
#include <hip/hip_runtime.h>

// MyConvT: masked ConvTranspose2d, B=8, Cin=192, Cout=128, 64x64 -> 128x128,
// K=5, S=2, P=2, OP=1.  out = pooled_mask ? (convT(x,w) + bias) : 0
// Round 13: r10 K-loop register budget (single bfr set — r12's bf double
// buffer spilled: FETCH/WRITE +7/+19MB) + PAIR-PHASES: one vmcnt gate +
// one barrier per 2 taps (13/round vs 25). 5-slot ring, global ledger:
// phase T stages taps {T+3,T+4} (tap-24 phase: only T+3) => slot writes
// (T+3,T+4)%5 disjoint from reads (T,T+1)%5; cross-round staging lands
// next round's taps {0,1,2} exactly like the prologue; steady gate
// vmcnt(6), tail 2/0. Fused prep kernel kept from r12.

#define NB   8
#define CIN  192
#define COUT 128
#define HH   64
#define OHH  128
#define OWW  128
#define MH   132
#define MW   132

#define X4_IYH_B 27648               // bytes per (b,iyH): 3 c3 x 72 rows x 128B
#define PLANE_B  9216                // one c3 plane slice: 72 rows x 128B
#define XBUF_B   36864               // 4 planes
#define WOFF     36864
#define NSLOT    5
#define LDS_B    (XBUF_B + NSLOT * 8192)   // 77,824 <= 81,920 (2 blocks/CU)

typedef short bf16x8 __attribute__((ext_vector_type(8)));
typedef float f32x4  __attribute__((ext_vector_type(4)));
typedef float f32x2  __attribute__((ext_vector_type(2)));

static __device__ __forceinline__ unsigned short f2bf(float f) {
  union { float f; unsigned int u; } a; a.f = f;
  return (unsigned short)((a.u + 0x7fffu + ((a.u >> 16) & 1u)) >> 16);   // RNE
}

#define GLOAD_LDS16(gp, lp) __builtin_amdgcn_global_load_lds(                      \
    (const __attribute__((address_space(1))) void*)(gp),                           \
    (__attribute__((address_space(3))) void*)(lp), 16, 0, 0)

// ---------------- fused prep: xpose (528) | wpack (96) | pool (128) --------
__global__ __launch_bounds__(256) void prep_k(
    const float* __restrict__ x, const int* __restrict__ mask,
    const float* __restrict__ w, unsigned short* __restrict__ x4,
    unsigned short* __restrict__ w4, unsigned char* __restrict__ many) {
  const int bid = blockIdx.x, tid = threadIdx.x;

  if (bid < 528) {                                   // ---- xpose ----
    const int b = bid / 66, iyH = bid % 66;
    const int lane = tid & 63, wv = tid >> 6;
    unsigned short* pl = x4 + (size_t)(b * 66 + iyH) * (X4_IYH_B / 2);

    if (iyH == 0 || iyH == 65) {                     // zero halo plane
      for (int i = tid; i < X4_IYH_B / 16; i += 256)
        *(uint4*)(pl + i * 8) = make_uint4(0, 0, 0, 0);
      return;
    }
    const int iy = iyH - 1;
    if (tid < 48) {                                  // halo rows 0,65 per c3
      int c3 = tid >> 4, rr = (tid >> 3) & 1, ch = tid & 7;
      *(uint4*)(pl + (c3 * 72 + rr * 65) * 64 + ch * 8) = make_uint4(0, 0, 0, 0);
    }
    #pragma unroll
    for (int k = 0; k < 6; ++k) {
      int ci0 = wv * 48 + k * 8;
      int c3 = ci0 >> 6, cr = ci0 & 63;
      unsigned short p[8];
      #pragma unroll
      for (int e = 0; e < 8; ++e)
        p[e] = f2bf(x[(((size_t)b * CIN + ci0 + e) * HH + iy) * HH + lane]);
      uint4 v;
      v.x = (unsigned)p[0] | ((unsigned)p[1] << 16);
      v.y = (unsigned)p[2] | ((unsigned)p[3] << 16);
      v.z = (unsigned)p[4] | ((unsigned)p[5] << 16);
      v.w = (unsigned)p[6] | ((unsigned)p[7] << 16);
      *(uint4*)(pl + ((size_t)c3 * 72 + 1 + lane) * 64 + cr) = v;
    }
  } else if (bid < 624) {                            // ---- wpack ----
    int idx = (bid - 528) * 256 + tid;               // 0..24575
    int ci = idx % CIN, co = idx / CIN;
    int cob = co >> 6, c = co & 63, c3 = ci >> 6, cir = ci & 63;
    const float* src = w + (size_t)(ci * COUT + co) * 25;
    #pragma unroll
    for (int tap = 0; tap < 25; ++tap)
      w4[(size_t)((tap * 2 + cob) * 3 + c3) * 4096 + c * 64 + cir] = f2bf(src[tap]);
  } else {                                           // ---- pool (4 ow/thr) ----
    int g = (bid - 624) * 256 + tid;                 // 0..32767
    int owq = g & 31, oh = (g >> 5) & 127, b = g >> 12;
    const int* mp = mask + (b * MH + oh) * MW + owq * 4;
    int a0 = 0, a1 = 0, a2 = 0, a3 = 0;
    #pragma unroll
    for (int i = 0; i < 5; ++i) {
      int4 u = *(const int4*)(mp + i * MW);
      int4 v = *(const int4*)(mp + i * MW + 4);
      int c = u.z | u.w | v.x;                       // cols +2,+3,+4
      a0 |= u.x | u.y | c;
      a1 |= u.y | c | v.y;
      a2 |= c | v.y | v.z;
      a3 |= u.w | v.x | v.y | v.z | v.w;
    }
    *(uchar4*)(many + ((size_t)b * OHH + oh) * OWW + owq * 4) =
        make_uchar4(a0 ? 1 : 0, a1 ? 1 : 0, a2 ? 1 : 0, a3 ? 1 : 0);
  }
}

// ------------------------------ main kernel --------------------------------
// flat tap order (pairs aligned to group starts):
// t:      0  1  2  3  4  5  6  7  8  9 10 11 12 13 14 15 16 17 18 19 20 21 22 23 24
// (kh,kw) 00 01 10 11 02 03 12 13 04 14 20 21 30 31 22 23 32 33 24 34 40 41 42 43 44

#define VMC(N) asm volatile("s_waitcnt vmcnt(" #N ")" ::: "memory")

#define GATE(T)                                                                \
  { if ((T) == 24 && c3 == 2)      VMC(0);                                     \
    else if ((T) == 22 && c3 == 2) VMC(2);                                     \
    else                           VMC(6);                                     \
    __builtin_amdgcn_s_barrier(); }

#define BF_LOAD(KK, KJ)                                                        \
  { const int p_ = oyr + 2 - (KK);                                             \
    _Pragma("unroll") for (int k2 = 0; k2 < 2; ++k2)                           \
      _Pragma("unroll") for (int ti = 0; ti < 4; ++ti) {                       \
        const int row_ = ti * 16 + l15 + 2 - (KJ);                             \
        bfr[k2][ti] = *(const bf16x8*)(lds + p_ * PLANE_B + row_ * 128 +       \
                                       (((k2 * 4 + kc) ^ (row_ & 7)) << 4)); } }

#define AF_LOADJ(J, T)                                                         \
  { const char* ws_ = lds + WOFF + ((T) % 5) * 8192;                           \
    _Pragma("unroll") for (int k2 = 0; k2 < 2; ++k2)                           \
      _Pragma("unroll") for (int mi = 0; mi < 2; ++mi) {                       \
        const int row_ = cos * 32 + mi * 16 + l15;                             \
        afr[J][k2][mi] = *(const bf16x8*)(ws_ + row_ * 128 +                   \
                                          (((k2 * 4 + kc) ^ (l15 & 7)) << 4)); } }

#define MMJ(J, PH_, PW_)                                                       \
  { __builtin_amdgcn_s_setprio(1);                                             \
    _Pragma("unroll") for (int k2 = 0; k2 < 2; ++k2)                           \
      _Pragma("unroll") for (int mi = 0; mi < 2; ++mi)                         \
        _Pragma("unroll") for (int ti = 0; ti < 4; ++ti)                       \
          acc[PH_][PW_][mi][ti] = __builtin_amdgcn_mfma_f32_16x16x32_bf16(     \
              afr[J][k2][mi], bfr[k2][ti], acc[PH_][PW_][mi][ti], 0, 0, 0);    \
    __builtin_amdgcn_s_setprio(0); }

// pair-phase: stage taps T+3,T+4 | gate+barrier | (bf reload) | af x2 | MFMA x32
#define PAIRB(T, KK, KJ, PH0, PW0, PH1, PW1)                                   \
  { stage_u((T) + 3); stage_u((T) + 4); GATE(T)                                \
    BF_LOAD(KK, KJ) AF_LOADJ(0, T) AF_LOADJ(1, (T) + 1)                        \
    MMJ(0, PH0, PW0) MMJ(1, PH1, PW1) }
#define PAIRN(T, PH0, PW0, PH1, PW1)                                           \
  { stage_u((T) + 3); stage_u((T) + 4); GATE(T)                                \
    AF_LOADJ(0, T) AF_LOADJ(1, (T) + 1)                                        \
    MMJ(0, PH0, PW0) MMJ(1, PH1, PW1) }
// single-tap phase (t=24): stages only T+3 (keeps cross-round ledger uniform)
#define PH1B(T, KK, KJ, PH0, PW0)                                              \
  { stage_u((T) + 3); GATE(T)                                                  \
    BF_LOAD(KK, KJ) AF_LOADJ(0, T) MMJ(0, PH0, PW0) }

// grid 512: bid&7 = b (== XCD); qq = bid>>3: cob = qq&1, oyq = qq>>1 (0..31).
// 256 thr = 4 waves: cos = wv&1 (co 32-half), oyr = wv>>1 (oy row of pair).
__global__ __launch_bounds__(256, 2) void convt_mfma(
    const unsigned short* __restrict__ x4, const unsigned short* __restrict__ w4,
    const float* __restrict__ bias, const unsigned char* __restrict__ many,
    float* __restrict__ out) {
  __shared__ __align__(16) char lds[LDS_B];
  // tapid (kh*5+kw) by flat tap index
  constexpr int TID[25] = {0,1,5,6, 2,3,7,8, 4,9, 10,11,15,16, 12,13,17,18,
                           14,19, 20,21, 22,23, 24};

  const int tid = threadIdx.x, lane = tid & 63, wv = tid >> 6;
  const int l15 = lane & 15, kc = lane >> 4;
  const int cos = wv & 1, oyr = wv >> 1;
  const int b = blockIdx.x & 7, qq = blockIdx.x >> 3;
  const int cob = qq & 1, oyq = qq >> 1;
  const int oy0 = oyq * 2, oy = oy0 + oyr;
  // inverse-permuted source lane offset (matches read-side XOR swizzle)
  const int sswz = (lane >> 3) * 128 + (((lane & 7) ^ (lane >> 3)) << 4);

  const char* x4b = (const char*)x4 + (size_t)(b * 66 + oy0) * X4_IYH_B;
  const char* w4b = (const char*)w4 + cob * 24576;

  f32x4 acc[2][2][2][4];                 // [ph][pw][mi][ti]
  #pragma unroll
  for (int p = 0; p < 2; ++p)
    #pragma unroll
    for (int q2 = 0; q2 < 2; ++q2)
      #pragma unroll
      for (int i = 0; i < 2; ++i)
        #pragma unroll
        for (int j = 0; j < 4; ++j)
          acc[p][q2][i][j] = (f32x4){0.f, 0.f, 0.f, 0.f};

  auto stage_x = [&](int c3) {
    #pragma unroll
    for (int j = 0; j < 9; ++j) {
      int qc = wv + 4 * j;                           // 36 chunks of 1KB
      int p = qc / 9, ch = qc % 9;
      GLOAD_LDS16(x4b + (size_t)p * X4_IYH_B + c3 * PLANE_B + ch * 1024 + sswz,
                  lds + p * PLANE_B + ch * 1024 + lane * 16);
    }
  };
  auto stage_w = [&](int tapid, int c3n, int slot) { // 2 x 1KB per wave
    const char* s = w4b + (size_t)tapid * 49152 + c3n * 8192 + wv * 2048 + sswz;
    char* d = lds + WOFF + slot * 8192 + wv * 2048 + lane * 16;
    GLOAD_LDS16(s, d);
    GLOAD_LDS16(s + 1024, d + 1024);
  };
  int c3 = 0;                                        // current ci64 round
  auto stage_u = [&](int u) {                        // stage local-or-next tap u
    if (u <= 24) stage_w(TID[u], c3, u % 5);
    else if (c3 < 2) stage_w(TID[u - 25], c3 + 1, (u - 25) % 5);
  };

  // ---- prologue: x round 0 + flat taps 0,1,2 (slots 0,1,2) ----
  stage_x(0);
  stage_w(TID[0], 0, 0);
  stage_w(TID[1], 0, 1);
  stage_w(TID[2], 0, 2);
  // no wait here: PAIRB(0)'s gate (vmcnt 6) admits taps 2..4 in flight.

  bf16x8 bfr[2][4], afr[2][2][2];
  #pragma unroll 1
  for (c3 = 0; c3 < 3; ++c3) {
    PAIRB(0,  0, 0,  0, 0,  0, 1)       // t0 (0,0), t1 (0,1) | bf g(kk0,kj0)
    PAIRN(2,         1, 0,  1, 1)       // t2 (1,0), t3 (1,1)
    PAIRB(4,  0, 1,  0, 0,  0, 1)       // t4 (0,2), t5 (0,3) | bf g(kk0,kj1)
    PAIRN(6,         1, 0,  1, 1)       // t6 (1,2), t7 (1,3)
    PAIRB(8,  0, 2,  0, 0,  1, 0)       // t8 (0,4), t9 (1,4) | bf g(kk0,kj2)
    PAIRB(10, 1, 0,  0, 0,  0, 1)       // t10 (2,0), t11 (2,1) | bf g(kk1,kj0)
    PAIRN(12,        1, 0,  1, 1)       // t12 (3,0), t13 (3,1)
    PAIRB(14, 1, 1,  0, 0,  0, 1)       // t14 (2,2), t15 (2,3) | bf g(kk1,kj1)
    PAIRN(16,        1, 0,  1, 1)       // t16 (3,2), t17 (3,3)
    PAIRB(18, 1, 2,  0, 0,  1, 0)       // t18 (2,4), t19 (3,4) | bf g(kk1,kj2)
    PAIRB(20, 2, 0,  0, 0,  0, 1)       // t20 (4,0), t21 (4,1) | bf g(kk2,kj0)
    PAIRB(22, 2, 1,  0, 0,  0, 1)       // t22 (4,2), t23 (4,3) | bf g(kk2,kj1)
    PH1B (24, 2, 2,  0, 0)              // t24 (4,4)           | bf g(kk2,kj2)
    if (c3 < 2) {                       // round boundary: restage x planes
      __builtin_amdgcn_s_barrier();     // all waves done reading xbuf
      stage_x(c3 + 1);
      VMC(0);                           // drains x + pre-staged next-round w
      __builtin_amdgcn_s_barrier();
    }
  }

  // ---- epilogue: bias + mask fused, fully-coalesced f32x2 stores ----
  const int cobase = cob * 64 + cos * 32;
  #pragma unroll
  for (int mi = 0; mi < 2; ++mi) {
    const f32x4 bv = *(const f32x4*)(bias + cobase + mi * 16 + kc * 4);
    #pragma unroll
    for (int ph = 0; ph < 2; ++ph) {
      const int oh = 2 * oy + ph;
      const unsigned char* mrow = many + ((size_t)b * OHH + oh) * OWW;
      #pragma unroll
      for (int ti = 0; ti < 4; ++ti) {
        const int ow0 = 2 * (ti * 16 + l15);
        const unsigned short m2 = *(const unsigned short*)(mrow + ow0);
        #pragma unroll
        for (int r = 0; r < 4; ++r) {
          const int co = cobase + mi * 16 + kc * 4 + r;
          f32x2 v;
          v.x = (m2 & 0x00FFu) ? acc[ph][0][mi][ti][r] + bv[r] : 0.f;
          v.y = (m2 & 0xFF00u) ? acc[ph][1][mi][ti][r] + bv[r] : 0.f;
          *(f32x2*)(out + (((size_t)(b * COUT + co)) * OHH + oh) * OWW + ow0) = v;
        }
      }
    }
  }
}

extern "C" void kernel_launch(void* const* d_in, const int* in_sizes, int n_in,
                              void* d_out, int out_size, void* d_ws, size_t ws_size,
                              hipStream_t stream) {
  const float* x    = (const float*)d_in[0];
  const int*   mask = (const int*)d_in[1];
  const float* w    = (const float*)d_in[2];
  const float* bias = (const float*)d_in[3];
  float* out = (float*)d_out;

  // ws: many 128KB | x4 14.6MB | w4 1.23MB  (~16MB)
  unsigned char*  many = (unsigned char*)d_ws;
  unsigned short* x4   = (unsigned short*)((char*)d_ws + 131072);
  unsigned short* w4   = (unsigned short*)((char*)d_ws + 131072 +
                                           (size_t)NB * 66 * X4_IYH_B);

  prep_k<<<752, 256, 0, stream>>>(x, mask, w, x4, w4, many);
  convt_mfma<<<512, 256, 0, stream>>>(x4, w4, bias, many, out);
}